// Round 4
// baseline (15496.201 us; speedup 1.0000x reference)
//
#include <hip/hip_runtime.h>
#include <hip/hip_bf16.h>
#include <hip/hip_cooperative_groups.h>

namespace cg = cooperative_groups;

// Problem constants
#define B 128
#define T 256
#define E 300
#define HH 256
#define O 5
#define NSTEP (2*T - 1)   // 511
#define NINT 255          // internal (reduce) nodes per batch
#define NBLK 256          // cooperative grid size

__device__ __forceinline__ float sigm(float x) { return 1.f / (1.f + __expf(-x)); }

// ---------------------------------------------------------------------------
// K0: transpose weights.
//   WcT[e][0:256] = Wp[h][e], WcT[e][256:512] = Wg[h][e]
//   WrT[k][j] = Wr[j][k]   (j in [0,1280), k in [0,512))  -- k-major for coalesced per-k loads
// ---------------------------------------------------------------------------
__global__ __launch_bounds__(256) void k_transpose(
    const float* __restrict__ Wp, const float* __restrict__ Wg,
    const float* __restrict__ Wr, float* __restrict__ WcT,
    float* __restrict__ WrT) {
  int idx = blockIdx.x * 256 + threadIdx.x;
  if (idx < HH * E) {
    int h = idx / E;
    int e = idx % E;
    WcT[e * 512 + h]       = Wp[idx];
    WcT[e * 512 + 256 + h] = Wg[idx];
  }
  if (idx < 5 * HH * 2 * HH) {   // 1280*512
    int j = idx / 512;
    int k = idx % 512;
    WrT[k * 1280 + j] = Wr[idx];
  }
}

// ---------------------------------------------------------------------------
// K1: leaf states. buffers[b][t][0:256]=h, [256:512]=c
// ---------------------------------------------------------------------------
#define TT 16
__global__ __launch_bounds__(256) void k_buffers(
    const int* __restrict__ x_ids, const float* __restrict__ embed,
    const float* __restrict__ WcT, const float* __restrict__ bp,
    const float* __restrict__ bg, float* __restrict__ buffers) {
  __shared__ float lds[TT * E];
  const int b  = blockIdx.y;
  const int t0 = blockIdx.x * TT;
  const int tid = threadIdx.x;

  for (int i = tid; i < TT * E; i += 256) {
    int t = i / E;
    int e = i % E;
    int id = x_ids[b * T + t0 + t];
    lds[i] = embed[(size_t)id * E + e];
  }
  __syncthreads();

  const int h = tid;
  float accP[TT], accG[TT];
#pragma unroll
  for (int t = 0; t < TT; ++t) { accP[t] = bp[h]; accG[t] = bg[h]; }

  for (int e = 0; e < E; ++e) {
    float wp = WcT[e * 512 + h];
    float wg = WcT[e * 512 + 256 + h];
#pragma unroll
    for (int t = 0; t < TT; ++t) {
      float x = lds[t * E + e];
      accP[t] = fmaf(x, wp, accP[t]);
      accG[t] = fmaf(x, wg, accG[t]);
    }
  }

#pragma unroll
  for (int t = 0; t < TT; ++t) {
    float c  = accP[t];
    float hb = tanhf(c) * sigm(accG[t]);
    size_t base = ((size_t)b * T + t0 + t) * 512;
    buffers[base + h]       = hb;
    buffers[base + 256 + h] = c;
  }
}

// ---------------------------------------------------------------------------
// K2: prep — simulate shift/reduce per batch element, assign tree levels,
// build level-ordered worklist. 1 block, 128 threads (one per batch elem).
// meta[b][r] = left | right<<9 | level<<18   (node id = 256+r)
// ---------------------------------------------------------------------------
__global__ __launch_bounds__(128) void k_prep(
    const int* __restrict__ trans, int* __restrict__ meta,
    int* __restrict__ levCnt, int* __restrict__ levOff, int* __restrict__ maxLevG,
    int* __restrict__ rootA, unsigned* __restrict__ worklist,
    unsigned short* __restrict__ stkG) {
  __shared__ int cnt[256];
  __shared__ int off[256];
  __shared__ int cur[256];
  const int b = threadIdx.x;
  for (int i = b; i < 256; i += 128) cnt[i] = 0;
  __syncthreads();

  int sp = 0, bp = T, r = 0;
  for (int s = 0; s < NSTEP; ++s) {
    int tr = trans[s * B + b];
    if (tr == 0) {                       // SHIFT: leaf id = bp-1, level 0
      stkG[sp * 128 + b] = (unsigned short)(bp - 1);
      sp++; bp--;
    } else {                             // REDUCE
      int idR = stkG[(sp - 1) * 128 + b];
      int idL = stkG[(sp - 2) * 128 + b];
      sp -= 2;
      int lL = (idL < 256) ? 0 : (meta[b * NINT + idL - 256] >> 18);
      int lR = (idR < 256) ? 0 : (meta[b * NINT + idR - 256] >> 18);
      int lev = max(lL, lR) + 1;
      meta[b * NINT + r] = idL | (idR << 9) | (lev << 18);
      atomicAdd(&cnt[lev], 1);
      stkG[sp * 128 + b] = (unsigned short)(256 + r);
      sp++; r++;
    }
  }
  rootA[b] = (int)stkG[0 * 128 + b];
  __syncthreads();

  if (b == 0) {
    int acc = 0, ml = 1;
    for (int l = 0; l < 256; ++l) {
      off[l] = acc; acc += cnt[l];
      if (cnt[l] > 0) ml = l;
    }
    *maxLevG = ml;
  }
  __syncthreads();
  for (int i = b; i < 256; i += 128) { levCnt[i] = cnt[i]; levOff[i] = off[i]; cur[i] = off[i]; }
  __syncthreads();

  for (int i = 0; i < NINT; ++i) {
    int lev = meta[b * NINT + i] >> 18;
    int pos = atomicAdd(&cur[lev], 1);
    worklist[pos] = (unsigned)((b << 9) | (256 + i));
  }
}

// ---------------------------------------------------------------------------
// K3: level-parallel TreeLSTM cell evaluation (cooperative).
// Work item = (group of 8 nodes, 64-wide h-slice). 256 threads:
//   thread (qw=tid>>6, hh=tid&63): owns Wr row j1 = qw*256+h0+hh (gates i,fl,fr,g)
//   over full k=512, + quarter of o-gate row j2 = 1024+h0+hh over k in
//   [qw*128, qw*128+128). 8 node-accumulators per row => 8x weight reuse.
// Child h values are wave-uniform -> scalar loads (readfirstlane-pinned ptrs).
// One grid.sync per level.
// ---------------------------------------------------------------------------
__global__ __launch_bounds__(256) void k_tree(
    const float* __restrict__ WrT, const float* __restrict__ br,
    const int* __restrict__ meta, const int* __restrict__ levCnt,
    const int* __restrict__ levOff, const int* __restrict__ maxLevG,
    const unsigned* __restrict__ worklist,
    const float* __restrict__ buffers, float* __restrict__ internal) {
  cg::grid_group grid = cg::this_grid();
  __shared__ float projM[4][64][9];   // [gate][hh][node] (+pad)
  __shared__ float projO[4][64][9];   // [k-quarter][hh][node]
  const int tid = threadIdx.x;
  const int hh = tid & 63;
  const int qw = tid >> 6;            // wave id: gate for main row, k-quarter for o-row
  const int maxLev = *maxLevG;

  for (int lev = 1; lev <= maxLev; ++lev) {
    const int cnt  = levCnt[lev];
    const int woff = levOff[lev];
    const int ngrp = (cnt + 7) >> 3;
    const int items = ngrp << 2;

    for (int item = blockIdx.x; item < items; item += gridDim.x) {
      const int grp = item >> 2;
      const int h0  = (item & 3) << 6;
      __syncthreads();   // guard proj LDS reuse across items

      // --- node meta: uniform child pointers ---
      const float* xl[8];
      const float* xr[8];
#pragma unroll
      for (int n = 0; n < 8; ++n) {
        int wi = woff + (grp << 3) + n;
        if (wi >= woff + cnt) wi = woff + cnt - 1;   // pad: duplicate last node
        unsigned w = worklist[wi];
        int node = __builtin_amdgcn_readfirstlane((int)(w & 511u));
        int bb   = __builtin_amdgcn_readfirstlane((int)(w >> 9));
        int m    = __builtin_amdgcn_readfirstlane(meta[bb * NINT + node - 256]);
        int il = m & 511, ir = (m >> 9) & 511;
        xl[n] = (il < 256) ? (buffers + (((size_t)bb * T + il) << 9))
                           : (internal + (((size_t)bb * NINT + il - 256) << 9));
        xr[n] = (ir < 256) ? (buffers + (((size_t)bb * T + ir) << 9))
                           : (internal + (((size_t)bb * NINT + ir - 256) << 9));
      }

      const int j1 = (qw << 8) + h0 + hh;   // gates 0..3
      const int j2 = 1024 + h0 + hh;        // o gate
      float a[8]  = {0, 0, 0, 0, 0, 0, 0, 0};
      float bq[8] = {0, 0, 0, 0, 0, 0, 0, 0};

      // main row, k = 0..255 (left h)
      for (int k0 = 0; k0 < 256; k0 += 4) {
        const float* wr = WrT + (size_t)k0 * 1280 + j1;
        float w0 = wr[0], w1 = wr[1280], w2 = wr[2560], w3 = wr[3840];
#pragma unroll
        for (int n = 0; n < 8; ++n) {
          const float* xp = xl[n] + k0;
          float s = a[n];
          s = fmaf(w0, xp[0], s);
          s = fmaf(w1, xp[1], s);
          s = fmaf(w2, xp[2], s);
          s = fmaf(w3, xp[3], s);
          a[n] = s;
        }
      }
      // main row, k = 256..511 (right h)
      for (int k0 = 0; k0 < 256; k0 += 4) {
        const float* wr = WrT + (size_t)(k0 + 256) * 1280 + j1;
        float w0 = wr[0], w1 = wr[1280], w2 = wr[2560], w3 = wr[3840];
#pragma unroll
        for (int n = 0; n < 8; ++n) {
          const float* xp = xr[n] + k0;
          float s = a[n];
          s = fmaf(w0, xp[0], s);
          s = fmaf(w1, xp[1], s);
          s = fmaf(w2, xp[2], s);
          s = fmaf(w3, xp[3], s);
          a[n] = s;
        }
      }
      // o-gate quarter row: k in [qw*128, qw*128+128)
      {
        const int kw = qw << 7;          // weight k offset
        const int kb = (qw & 1) << 7;    // offset within child h
        const bool useL = (qw < 2);
        for (int k0 = 0; k0 < 128; k0 += 4) {
          const float* wr = WrT + (size_t)(kw + k0) * 1280 + j2;
          float w0 = wr[0], w1 = wr[1280], w2 = wr[2560], w3 = wr[3840];
#pragma unroll
          for (int n = 0; n < 8; ++n) {
            const float* xp = (useL ? xl[n] : xr[n]) + kb + k0;
            float s = bq[n];
            s = fmaf(w0, xp[0], s);
            s = fmaf(w1, xp[1], s);
            s = fmaf(w2, xp[2], s);
            s = fmaf(w3, xp[3], s);
            bq[n] = s;
          }
        }
      }

      // --- exchange partials via LDS ---
#pragma unroll
      for (int n = 0; n < 8; ++n) {
        projM[qw][hh][n] = a[n];
        projO[qw][hh][n] = bq[n];
      }
      __syncthreads();

      // --- combine: thread (qw,hh) handles nodes n = qw, qw+4 ---
#pragma unroll
      for (int half = 0; half < 2; ++half) {
        int n = qw + (half << 2);
        float p0 = projM[0][hh][n] + br[0 * 256 + h0 + hh];
        float p1 = projM[1][hh][n] + br[1 * 256 + h0 + hh];
        float p2 = projM[2][hh][n] + br[2 * 256 + h0 + hh];
        float p3 = projM[3][hh][n] + br[3 * 256 + h0 + hh];
        float po = projO[0][hh][n] + projO[1][hh][n] + projO[2][hh][n] + projO[3][hh][n]
                 + br[1024 + h0 + hh];
        int wi = woff + (grp << 3) + n;
        if (wi >= woff + cnt) wi = woff + cnt - 1;
        unsigned w = worklist[wi];
        int node = (int)(w & 511u);
        int bb   = (int)(w >> 9);
        int m = meta[bb * NINT + node - 256];
        int il = m & 511, ir = (m >> 9) & 511;
        const float* cls = (il < 256) ? (buffers + (((size_t)bb * T + il) << 9))
                                      : (internal + (((size_t)bb * NINT + il - 256) << 9));
        const float* crs = (ir < 256) ? (buffers + (((size_t)bb * T + ir) << 9))
                                      : (internal + (((size_t)bb * NINT + ir - 256) << 9));
        float cl = cls[256 + h0 + hh];
        float cr = crs[256 + h0 + hh];
        float ci  = sigm(p0);
        float cfl = sigm(p1);
        float cfr = sigm(p2);
        float tg  = tanhf(p3);
        float co  = sigm(po);
        float cn  = ci * tg + cfl * cl + cfr * cr;
        float hn  = co * tanhf(cn);
        float* dst = internal + (((size_t)bb * NINT + node - 256) << 9);
        dst[h0 + hh]       = hn;   // duplicate-pad writes same value: benign
        dst[256 + h0 + hh] = cn;
      }
    }
    __threadfence();
    grid.sync();
  }
}

// ---------------------------------------------------------------------------
// K4: logits = root_h @ Wo^T + bo
// ---------------------------------------------------------------------------
__global__ __launch_bounds__(256) void k_out(
    const float* __restrict__ Wo, const float* __restrict__ bo,
    const int* __restrict__ rootA, const float* __restrict__ buffers,
    const float* __restrict__ internal, float* __restrict__ out) {
  const int b = blockIdx.x;
  const int tid = threadIdx.x;
  __shared__ float red[256];
  int rid = rootA[b];
  const float* hsrc = (rid < 256) ? (buffers + (((size_t)b * T + rid) << 9))
                                  : (internal + (((size_t)b * NINT + rid - 256) << 9));
  float hj = hsrc[tid];
  for (int m = 0; m < O; ++m) {
    red[tid] = Wo[m * HH + tid] * hj;
    __syncthreads();
    for (int off = 128; off > 0; off >>= 1) {
      if (tid < off) red[tid] += red[tid + off];
      __syncthreads();
    }
    if (tid == 0) out[b * O + m] = red[0] + bo[m];
    __syncthreads();
  }
}

// ---------------------------------------------------------------------------
extern "C" void kernel_launch(void* const* d_in, const int* in_sizes, int n_in,
                              void* d_out, int out_size, void* d_ws, size_t ws_size,
                              hipStream_t stream) {
  const int*   x_ids = (const int*)d_in[0];
  const int*   trans = (const int*)d_in[1];
  const float* embed = (const float*)d_in[2];
  const float* Wp    = (const float*)d_in[3];
  const float* bp    = (const float*)d_in[4];
  const float* Wg    = (const float*)d_in[5];
  const float* bg    = (const float*)d_in[6];
  const float* Wr    = (const float*)d_in[7];
  const float* br    = (const float*)d_in[8];
  const float* Wo    = (const float*)d_in[9];
  const float* bo    = (const float*)d_in[10];
  float* out = (float*)d_out;

  float* ws       = (float*)d_ws;
  float* WcT      = ws;                                   // 300*512
  float* WrT      = WcT + 300 * 512;                      // 512*1280
  float* buffers  = WrT + 512 * 1280;                     // B*T*512
  float* internal = buffers + (size_t)B * T * 512;        // B*NINT*512
  int*   meta     = (int*)(internal + (size_t)B * NINT * 512);  // B*NINT
  int*   levCnt   = meta + B * NINT;                      // 256
  int*   levOff   = levCnt + 256;                         // 256
  int*   maxLevG  = levOff + 256;                         // 1
  int*   rootA    = maxLevG + 1;                          // B
  unsigned* worklist = (unsigned*)(rootA + B);            // B*NINT = 32640
  unsigned short* stkG = (unsigned short*)(worklist + B * NINT);  // 128*256 u16

  k_transpose<<<(5 * HH * 2 * HH + 255) / 256, 256, 0, stream>>>(Wp, Wg, Wr, WcT, WrT);
  k_buffers<<<dim3(T / TT, B), 256, 0, stream>>>(x_ids, embed, WcT, bp, bg, buffers);
  k_prep<<<1, 128, 0, stream>>>(trans, meta, levCnt, levOff, maxLevG, rootA, worklist, stkG);

  {
    void* args[] = {(void*)&WrT, (void*)&br, (void*)&meta, (void*)&levCnt, (void*)&levOff,
                    (void*)&maxLevG, (void*)&worklist, (void*)&buffers, (void*)&internal};
    hipLaunchCooperativeKernel((void*)k_tree, dim3(NBLK), dim3(256), args, 0, stream);
  }

  k_out<<<B, 256, 0, stream>>>(Wo, bo, rootA, buffers, internal, out);
}